// Round 6
// baseline (502.021 us; speedup 1.0000x reference)
//
#include <hip/hip_runtime.h>

typedef float f32x2 __attribute__((ext_vector_type(2)));
typedef float f32x4 __attribute__((ext_vector_type(4)));
typedef _Float16 h16x2 __attribute__((ext_vector_type(2)));
typedef __fp16 fp16x2_raw __attribute__((ext_vector_type(2)));

#define LOG2E 1.44269504088896340736f

static __device__ __forceinline__ float rcp_fast(float x) { return __builtin_amdgcn_rcpf(x); }

static __device__ __forceinline__ f32x2 mk2(float a, float b) { f32x2 v; v[0] = a; v[1] = b; return v; }

static __device__ __forceinline__ float sigmoid_fast(float x) {
    // 1/(1+exp(-x)); exp2 overflow -> inf -> rcp -> 0 (correct limit), no NaN
    return rcp_fast(1.0f + __builtin_amdgcn_exp2f(-LOG2E * x));
}

static __device__ __forceinline__ float tanh_fast(float x) {
    float a = __builtin_fabsf(x);
    float t = __builtin_amdgcn_exp2f(-2.0f * LOG2E * a);
    float r = (1.0f - t) * rcp_fast(1.0f + t);
    return __builtin_copysignf(r, x);
}

// v_dot2_f32_f16: c += a[0]*b[0] + a[1]*b[1] (f32 accumulate)
static __device__ __forceinline__ float fdot2(h16x2 a, h16x2 b, float c) {
#if __has_builtin(__builtin_amdgcn_fdot2)
    return __builtin_amdgcn_fdot2(a, b, c, false);
#else
    return c + (float)(a[0]) * (float)(b[0]) + (float)(a[1]) * (float)(b[1]);
#endif
}

// v_cvt_pkrtz_f16_f32 returns an __fp16 vector; bit-cast to _Float16 vector
static __device__ __forceinline__ h16x2 pk(float a, float b) {
    fp16x2_raw r = __builtin_amdgcn_cvt_pkrtz(a, b);
    return __builtin_bit_cast(h16x2, r);
}

// 16 contiguous floats -> 8 f32x2 (preamble only)
static __device__ __forceinline__ void load_pairs16(const float* p, f32x2* dst) {
    const f32x4* q4 = (const f32x4*)p;
    f32x4 a = q4[0], b = q4[1], c = q4[2], d = q4[3];
    dst[0] = __builtin_shufflevector(a, a, 0, 1);
    dst[1] = __builtin_shufflevector(a, a, 2, 3);
    dst[2] = __builtin_shufflevector(b, b, 0, 1);
    dst[3] = __builtin_shufflevector(b, b, 2, 3);
    dst[4] = __builtin_shufflevector(c, c, 0, 1);
    dst[5] = __builtin_shufflevector(c, c, 2, 3);
    dst[6] = __builtin_shufflevector(d, d, 0, 1);
    dst[7] = __builtin_shufflevector(d, d, 2, 3);
}

// FULL-STATE-PER-LANE design: 16 lanes per batch, 4 batches per wave
// (2048 waves = 2/SIMD). Every lane keeps the ENTIRE 12-dim state vector in
// registers (replicated within its 16-lane group; bitwise identical since all
// inputs are identical). Per step the ONLY cross-lane op is one ds_bpermute
// all-gather of h; W_out@h (12x16) is computed redundantly per lane, renorm
// and LN stats are local. Weights are f16 pairs for v_dot2_f32_f16.
// __launch_bounds__(64,1): relaxes the allocator's occupancy target (which at
// (64,2) capped VGPRs at 128 and sank loop-invariant weights into per-step L2
// reloads -- the hidden chain component). Demand ~230 VGPR still leaves 2
// waves/SIMD resident (512-reg pool).
__global__ __launch_bounds__(64, 1) void vm_kernel(
    const float* __restrict__ init_state,  // (B,1,12)
    const float* __restrict__ commands,    // (B,T,4)
    const float* __restrict__ ln_g,        // (16)
    const float* __restrict__ ln_b,        // (16)
    const float* __restrict__ W_in,        // (16,16)
    const float* __restrict__ b_in,        // (16)
    const float* __restrict__ W_ih,        // (64,16)
    const float* __restrict__ W_hh,        // (64,16)
    const float* __restrict__ b_ih,        // (64)
    const float* __restrict__ b_hh,        // (64)
    const float* __restrict__ W_out,       // (12,16)
    const float* __restrict__ b_out,       // (12)
    float* __restrict__ out,               // (B,T,12)
    int B, int T)
{
    const int lane = threadIdx.x;
    const int j = lane & 15;
    const int g = lane >> 4;
    const int b = blockIdx.x * 4 + g;
    const int gbase = (lane & 48) << 2;     // byte addr of own group's lane 0

    // ---- preamble: gate-weight fold (identical math to verified R1/R5) ----
    f32x2 Wih[4][8], Wh32[4][8];
#pragma unroll
    for (int q = 0; q < 4; ++q) {
        load_pairs16(W_ih + (q * 16 + j) * 16, Wih[q]);
        load_pairs16(W_hh + (q * 16 + j) * 16, Wh32[q]);
    }

    // W_eff = W_ih @ W_in (row q*16+j), plus b_in fold
    f32x2 Wgx[4][8];
    float binacc[4];
#pragma unroll
    for (int q = 0; q < 4; ++q) {
        binacc[q] = 0.0f;
#pragma unroll
        for (int k2 = 0; k2 < 8; ++k2) Wgx[q][k2] = mk2(0.0f, 0.0f);
    }
#pragma unroll
    for (int m = 0; m < 16; ++m) {
        f32x2 wm[8];
        load_pairs16(W_in + m * 16, wm);    // uniform address -> scalar loads
        float bm = b_in[m];
#pragma unroll
        for (int q = 0; q < 4; ++q) {
            float wim = Wih[q][m >> 1][m & 1];
            f32x2 w2 = mk2(wim, wim);
#pragma unroll
            for (int k2 = 0; k2 < 8; ++k2) Wgx[q][k2] += w2 * wm[k2];
            binacc[q] += wim * bm;
        }
    }
    // fold LN gamma/beta: gate = dot(Wgx,x)*inv - mu*inv*sg + cst + dot(Wh,h)
    float sg[4], cst[4];
    {
        f32x2 gg2[8], bt2[8];
        load_pairs16(ln_g, gg2);
        load_pairs16(ln_b, bt2);
#pragma unroll
        for (int q = 0; q < 4; ++q) {
            f32x2 ss = mk2(0.0f, 0.0f), cc = mk2(0.0f, 0.0f);
#pragma unroll
            for (int k2 = 0; k2 < 8; ++k2) {
                cc += Wgx[q][k2] * bt2[k2];  // beta applied to pre-gamma W_eff
                Wgx[q][k2] *= gg2[k2];
                ss += Wgx[q][k2];
            }
            sg[q]  = ss[0] + ss[1];
            cst[q] = cc[0] + cc[1] + binacc[q] + b_ih[q * 16 + j] + b_hh[q * 16 + j];
        }
    }

    // gate weights -> f16 pairs
    h16x2 WgxH[4][8], WhH[4][8];
#pragma unroll
    for (int q = 0; q < 4; ++q)
#pragma unroll
        for (int k2 = 0; k2 < 8; ++k2) {
            WgxH[q][k2] = pk(Wgx[q][k2][0], Wgx[q][k2][1]);
            WhH[q][k2]  = pk(Wh32[q][k2][0], Wh32[q][k2][1]);
        }

    // FULL W_out (12 rows x 16) per lane, f16 pairs; wave-uniform addresses
    h16x2 WoF[12][8];
    float boF[12];
#pragma unroll
    for (int i = 0; i < 12; ++i) {
        f32x2 wo32[8];
        load_pairs16(W_out + i * 16, wo32);
#pragma unroll
        for (int k2 = 0; k2 < 8; ++k2) WoF[i][k2] = pk(wo32[k2][0], wo32[k2][1]);
        boF[i] = b_out[i];
    }

    const h16x2 one2 = pk(1.0f, 1.0f);

    // ---- full state vector, replicated per lane ----
    float st[12];
    {
        const f32x4* isp = (const f32x4*)(init_state + b * 12);  // 48B-aligned
        f32x4 s0 = isp[0], s1 = isp[1], s2 = isp[2];
#pragma unroll
        for (int i = 0; i < 4; ++i) {
            st[i] = s0[i]; st[4 + i] = s1[i]; st[8 + i] = s2[i];
        }
    }
    float c = 0.0f;
    h16x2 hpk[8];
#pragma unroll
    for (int k2 = 0; k2 < 8; ++k2) hpk[k2] = pk(0.0f, 0.0f);

    const f32x4* cmd4 = (const f32x4*)(commands + (size_t)b * T * 4);
    float* outp = out + (size_t)b * T * 12 + j * 4;   // lanes j<3 store f32x4

    // all-gather the own-group value v into 16 registers via bpermute
#define GATHER16(v, dst)                                                      \
    do {                                                                      \
        int _s = __float_as_int(v);                                           \
        _Pragma("unroll")                                                     \
        for (int _i = 0; _i < 16; ++_i)                                       \
            dst[_i] = __int_as_float(                                         \
                __builtin_amdgcn_ds_bpermute(gbase + (_i << 2), _s));         \
    } while (0)

    // pack x = [st(12), cmd(4)] into 8 f16 pairs
#define PACK_X(xpk, cv)                                                       \
    do {                                                                      \
        xpk[0] = pk(st[0], st[1]);  xpk[1] = pk(st[2], st[3]);                \
        xpk[2] = pk(st[4], st[5]);  xpk[3] = pk(st[6], st[7]);                \
        xpk[4] = pk(st[8], st[9]);  xpk[5] = pk(st[10], st[11]);              \
        xpk[6] = pk(cv[0], cv[1]);  xpk[7] = pk(cv[2], cv[3]);                \
    } while (0)

    // ---- prologue: x0 = raw init state || cmd0 (no initial renorm) ----
    h16x2 xpk[8];
    float mu, inv;
    {
        f32x4 cmd0 = cmd4[0];
        PACK_X(xpk, cmd0);
        float s0 = 0.0f, s1 = 0.0f, q0 = 0.0f, q1 = 0.0f;
#pragma unroll
        for (int i = 0; i < 4; ++i) {
            s0 = fdot2(xpk[i], one2, s0);
            s1 = fdot2(xpk[i + 4], one2, s1);
            q0 = fdot2(xpk[i], xpk[i], q0);
            q1 = fdot2(xpk[i + 4], xpk[i + 4], q1);
        }
        mu = (s0 + s1) * 0.0625f;
        float var = (q0 + q1) * 0.0625f - mu * mu;
        inv = __builtin_amdgcn_rsqf(var + 1e-5f);
    }

    // 2-deep command prefetch (float4 per step, identical across group lanes)
    f32x4 cmdS = cmd4[T > 1 ? 1 : 0];
    f32x4 cmdN = cmd4[T > 2 ? 2 : 0];

    for (int t = 0; t < T; ++t) {
        // ---- gates for own hidden j ----
        float gx[4], gh[4];
#pragma unroll
        for (int q = 0; q < 4; ++q) {
            float a0 = 0.0f, a1 = 0.0f, h0 = 0.0f, h1 = 0.0f;
#pragma unroll
            for (int k = 0; k < 4; ++k) {
                a0 = fdot2(WgxH[q][k], xpk[k], a0);
                a1 = fdot2(WgxH[q][k + 4], xpk[k + 4], a1);
                h0 = fdot2(WhH[q][k], hpk[k], h0);
                h1 = fdot2(WhH[q][k + 4], hpk[k + 4], h1);
            }
            gx[q] = a0 + a1;
            gh[q] = h0 + h1;
        }
        float nmi = -mu * inv;
        float gi = __builtin_fmaf(gx[0], inv, __builtin_fmaf(nmi, sg[0], cst[0] + gh[0]));
        float gf = __builtin_fmaf(gx[1], inv, __builtin_fmaf(nmi, sg[1], cst[1] + gh[1]));
        float gG = __builtin_fmaf(gx[2], inv, __builtin_fmaf(nmi, sg[2], cst[2] + gh[2]));
        float go = __builtin_fmaf(gx[3], inv, __builtin_fmaf(nmi, sg[3], cst[3] + gh[3]));

        float iv = sigmoid_fast(gi);
        float fv = sigmoid_fast(gf);
        float gv = tanh_fast(gG);
        float ov = sigmoid_fast(go);
        c = fv * c + iv * gv;
        float hv = ov * tanh_fast(c);

        // ---- the single cross-lane op: h all-gather + pack ----
        {
            float hg[16];
            GATHER16(hv, hg);
#pragma unroll
            for (int i = 0; i < 8; ++i) hpk[i] = pk(hg[2 * i], hg[2 * i + 1]);
        }

        // ---- full W_out @ h, replicated per lane (f32 accumulate) ----
#pragma unroll
        for (int i = 0; i < 12; ++i) {
            float d0 = 0.0f, d1 = 0.0f;
#pragma unroll
            for (int k = 0; k < 4; ++k) {
                d0 = fdot2(WoF[i][k], hpk[k], d0);
                d1 = fdot2(WoF[i][k + 4], hpk[k + 4], d1);
            }
            st[i] = st[i] + (d0 + d1) + boF[i];
        }

        // ---- sincos pair renorm, fully local ----
#pragma unroll
        for (int p = 0; p < 3; ++p) {
            float a = st[1 + 2 * p], bq = st[2 + 2 * p];
            float r = rcp_fast(__builtin_amdgcn_sqrtf(a * a + bq * bq) + 1e-8f);
            st[1 + 2 * p] = a * r; st[2 + 2 * p] = bq * r;
        }

        // ---- store: lanes 0..2 write f32x4 slices (cndmask-selected) ----
        {
            f32x4 v0, v1, v2;
#pragma unroll
            for (int i = 0; i < 4; ++i) { v0[i] = st[i]; v1[i] = st[4 + i]; v2[i] = st[8 + i]; }
            f32x4 w = (j == 1) ? v1 : v0;
            w = (j == 2) ? v2 : w;
            if (j < 3) *(f32x4*)outp = w;
            outp += 12;
        }

        // ---- next x: pack locally + LN stats ----
        PACK_X(xpk, cmdS);
        float s0 = 0.0f, s1 = 0.0f, q0 = 0.0f, q1 = 0.0f;
#pragma unroll
        for (int i = 0; i < 4; ++i) {
            s0 = fdot2(xpk[i], one2, s0);
            s1 = fdot2(xpk[i + 4], one2, s1);
            q0 = fdot2(xpk[i], xpk[i], q0);
            q1 = fdot2(xpk[i + 4], xpk[i + 4], q1);
        }
        mu = (s0 + s1) * 0.0625f;
        float var = (q0 + q1) * 0.0625f - mu * mu;
        inv = __builtin_amdgcn_rsqf(var + 1e-5f);

        // rotate 2-deep cmd prefetch
        cmdS = cmdN;
        int tn = t + 3;
        if (tn > T - 1) tn = T - 1;
        cmdN = cmd4[tn];
    }
#undef GATHER16
#undef PACK_X
}

extern "C" void kernel_launch(void* const* d_in, const int* in_sizes, int n_in,
                              void* d_out, int out_size, void* d_ws, size_t ws_size,
                              hipStream_t stream) {
    const float* init_state = (const float*)d_in[0];
    const float* commands   = (const float*)d_in[1];
    const float* ln_g       = (const float*)d_in[2];
    const float* ln_b       = (const float*)d_in[3];
    const float* W_in       = (const float*)d_in[4];
    const float* b_in       = (const float*)d_in[5];
    const float* W_ih       = (const float*)d_in[6];
    const float* W_hh       = (const float*)d_in[7];
    const float* b_ih       = (const float*)d_in[8];
    const float* b_hh       = (const float*)d_in[9];
    const float* W_out      = (const float*)d_in[10];
    const float* b_out      = (const float*)d_in[11];

    int B = in_sizes[0] / 12;           // 8192
    int T = in_sizes[1] / (B * 4);      // 256

    int blocks = B / 4;                 // 4 batch elements per 64-thread wave
    vm_kernel<<<blocks, 64, 0, stream>>>(init_state, commands, ln_g, ln_b,
                                         W_in, b_in, W_ih, W_hh, b_ih, b_hh,
                                         W_out, b_out, (float*)d_out, B, T);
}